// Round 1
// baseline (378.563 us; speedup 1.0000x reference)
//
#include <hip/hip_runtime.h>
#include <stdint.h>

#define BB 32
#define AA 8400
#define CC 80
#define MM 64
#define KTOP 13
#define FEPS 1e-9f

__device__ __forceinline__ float iou_fn(float gx1, float gy1, float gx2, float gy2,
                                        float px1, float py1, float px2, float py2) {
    float ix1 = fmaxf(gx1, px1), iy1 = fmaxf(gy1, py1);
    float ix2 = fminf(gx2, px2), iy2 = fminf(gy2, py2);
    float ov = fmaxf(ix2 - ix1, 0.0f) * fmaxf(iy2 - iy1, 0.0f);
    float a1 = fmaxf(gx2 - gx1, 0.0f) * fmaxf(gy2 - gy1, 0.0f);
    float a2 = fmaxf(px2 - px1, 0.0f) * fmaxf(py2 - py1, 0.0f);
    return ov / (a1 + a2 - ov + FEPS);
}

// Kernel 1: per (b,m) GT row, compute metrics over all anchors into LDS,
// then iterative top-13 argmax with JAX tie semantics (ties -> lower index).
__global__ __launch_bounds__(256) void topk_kernel(
    const float* __restrict__ pred_scores, const float* __restrict__ pred_bboxes,
    const float* __restrict__ anchors, const int* __restrict__ gt_labels,
    const float* __restrict__ gt_bboxes, const float* __restrict__ pad_mask,
    int* __restrict__ topk_out)
{
    __shared__ float met[AA];
    __shared__ float sval[256];
    __shared__ int   sidx[256];
    int bm = blockIdx.x;
    if (pad_mask[bm] == 0.0f) return;   // padded GT: topk never consumed (scatter checks pad)
    int b = bm / MM;
    int t = threadIdx.x;
    float gx1 = gt_bboxes[bm * 4 + 0], gy1 = gt_bboxes[bm * 4 + 1];
    float gx2 = gt_bboxes[bm * 4 + 2], gy2 = gt_bboxes[bm * 4 + 3];
    int label = gt_labels[bm];
    const float* pb = pred_bboxes + (size_t)b * AA * 4;
    const float* ps = pred_scores + (size_t)b * AA * CC + label;
    for (int a = t; a < AA; a += 256) {
        float px = anchors[a * 2 + 0], py = anchors[a * 2 + 1];
        float4 p = *(const float4*)(pb + a * 4);
        float iou = iou_fn(gx1, gy1, gx2, gy2, p.x, p.y, p.z, p.w);
        float d = fminf(fminf(px - gx1, py - gy1), fminf(gx2 - px, gy2 - py));
        float s = ps[(size_t)a * CC];
        float i2 = iou * iou;
        float al = s * (i2 * i2 * i2);
        met[a] = (d > FEPS) ? al : 0.0f;
    }
    __syncthreads();
    for (int k = 0; k < KTOP; ++k) {
        float bv = -2.0f; int bi = AA;
        for (int a = t; a < AA; a += 256) {
            float v = met[a];
            if (v > bv || (v == bv && a < bi)) { bv = v; bi = a; }
        }
        sval[t] = bv; sidx[t] = bi;
        __syncthreads();
        for (int s = 128; s > 0; s >>= 1) {
            if (t < s) {
                float ov = sval[t + s]; int oi = sidx[t + s];
                if (ov > sval[t] || (ov == sval[t] && oi < sidx[t])) { sval[t] = ov; sidx[t] = oi; }
            }
            __syncthreads();
        }
        if (t == 0) {
            int w = sidx[0];
            topk_out[bm * KTOP + k] = w;
            met[w] = -1.0f;   // metrics >= 0, so never re-picked
        }
        __syncthreads();
    }
}

// Kernel 2: scatter stage-1 mask_positive bits into a per-anchor 64-bit mask.
// mask1 = is_in_topk * is_in_gts * pad  (re-check in_gts here; pad here).
__global__ void scatter_kernel(
    const int* __restrict__ topk_idx, const float* __restrict__ anchors,
    const float* __restrict__ gt_bboxes, const float* __restrict__ pad_mask,
    unsigned long long* __restrict__ mask64)
{
    int t = blockIdx.x * blockDim.x + threadIdx.x;
    if (t >= BB * MM * KTOP) return;
    int bm = t / KTOP; int k = t % KTOP;
    if (pad_mask[bm] == 0.0f) return;
    int b = bm / MM; int m = bm % MM;
    int a = topk_idx[bm * KTOP + k];
    float gx1 = gt_bboxes[bm * 4 + 0], gy1 = gt_bboxes[bm * 4 + 1];
    float gx2 = gt_bboxes[bm * 4 + 2], gy2 = gt_bboxes[bm * 4 + 3];
    float px = anchors[a * 2 + 0], py = anchors[a * 2 + 1];
    float d = fminf(fminf(px - gx1, py - gy1), fminf(gx2 - px, gy2 - py));
    if (d > FEPS) atomicOr(&mask64[(size_t)b * AA + a], 1ull << m);
}

// Kernel 3: per anchor — resolve multi-assignment via first-argmax of IoU over
// ALL m (incl. padded, as the reference does), write labels/bboxes, record
// assigned m + align, and atomicMax per-GT max_metrics / max_ious.
__global__ void resolve_kernel(
    const float* __restrict__ pred_scores, const float* __restrict__ pred_bboxes,
    const int* __restrict__ gt_labels, const float* __restrict__ gt_bboxes,
    const int* __restrict__ bg_ptr,
    const unsigned long long* __restrict__ mask64,
    float* __restrict__ out_labels, float* __restrict__ out_bboxes,
    int* __restrict__ assigned_m, float* __restrict__ assigned_align,
    unsigned int* __restrict__ maxmet, unsigned int* __restrict__ maxiou)
{
    int t = blockIdx.x * blockDim.x + threadIdx.x;
    if (t >= BB * AA) return;
    int b = t / AA; int a = t % AA;
    unsigned long long mask = mask64[t];
    int cnt = __popcll(mask);
    float4 p = *(const float4*)(pred_bboxes + (size_t)t * 4);
    int mstar = -1;
    if (cnt == 1) {
        mstar = __ffsll(mask) - 1;
    } else if (cnt > 1) {
        float best = -1.0f; int bi = 0;
        for (int m = 0; m < MM; ++m) {
            const float* g = gt_bboxes + (size_t)(b * MM + m) * 4;
            float iou = iou_fn(g[0], g[1], g[2], g[3], p.x, p.y, p.z, p.w);
            if (iou > best) { best = iou; bi = m; }   // strict > : first occurrence
        }
        mstar = bi;
    }
    assigned_m[t] = mstar;
    int bidx = (mstar >= 0) ? mstar : 0;   // argmax of all-zero column = 0
    const float* g = gt_bboxes + (size_t)(b * MM + bidx) * 4;
    float g0 = g[0], g1 = g[1], g2 = g[2], g3 = g[3];
    out_bboxes[(size_t)t * 4 + 0] = g0;
    out_bboxes[(size_t)t * 4 + 1] = g1;
    out_bboxes[(size_t)t * 4 + 2] = g2;
    out_bboxes[(size_t)t * 4 + 3] = g3;
    out_labels[t] = (mstar >= 0) ? (float)gt_labels[b * MM + mstar] : (float)(*bg_ptr);
    if (mstar >= 0) {
        float iou = iou_fn(g0, g1, g2, g3, p.x, p.y, p.z, p.w);
        int label = gt_labels[b * MM + mstar];
        float s = pred_scores[(size_t)b * AA * CC + (size_t)a * CC + label];
        float i2 = iou * iou;
        float al = s * (i2 * i2 * i2);
        assigned_align[t] = al;
        // values >= 0: float ordering == uint-bit ordering
        atomicMax(&maxmet[b * MM + mstar], __float_as_uint(al));
        atomicMax(&maxiou[b * MM + mstar], __float_as_uint(iou));
    }
}

// Kernel 4: write assigned_scores (B,A,80) as coalesced float4s.
__global__ void scores_kernel(
    const int* __restrict__ gt_labels,
    const int* __restrict__ assigned_m, const float* __restrict__ assigned_align,
    const unsigned int* __restrict__ maxmet, const unsigned int* __restrict__ maxiou,
    float* __restrict__ out_scores)
{
    int t = blockIdx.x * blockDim.x + threadIdx.x;   // over B*A*20 float4s
    if (t >= BB * AA * (CC / 4)) return;
    int anchor = t / (CC / 4); int j = t % (CC / 4);
    int m = assigned_m[anchor];
    float4 v = make_float4(0.0f, 0.0f, 0.0f, 0.0f);
    if (m >= 0) {
        int b = anchor / AA;
        int label = gt_labels[b * MM + m];
        int base = j * 4;
        if (label >= base && label < base + 4) {
            float mm = __uint_as_float(maxmet[b * MM + m]);
            float mi = __uint_as_float(maxiou[b * MM + m]);
            float scale = assigned_align[anchor] / (mm + FEPS) * mi;
            ((float*)&v)[label - base] = scale;
        }
    }
    *(float4*)(out_scores + (size_t)t * 4) = v;
}

extern "C" void kernel_launch(void* const* d_in, const int* in_sizes, int n_in,
                              void* d_out, int out_size, void* d_ws, size_t ws_size,
                              hipStream_t stream) {
    const float* pred_scores = (const float*)d_in[0];
    const float* pred_bboxes = (const float*)d_in[1];
    const float* anchors     = (const float*)d_in[2];
    const int*   gt_labels   = (const int*)d_in[3];
    const float* gt_bboxes   = (const float*)d_in[4];
    const float* pad_mask    = (const float*)d_in[5];
    const int*   bg_ptr      = (const int*)d_in[6];

    // Workspace layout
    char* ws = (char*)d_ws;
    int*                topk_idx       = (int*)ws;                          // B*M*13 ints
    size_t off = (size_t)BB * MM * KTOP * sizeof(int);
    off = (off + 7) & ~(size_t)7;
    unsigned long long* mask64         = (unsigned long long*)(ws + off);   // B*A u64
    off += (size_t)BB * AA * sizeof(unsigned long long);
    int*                assigned_m     = (int*)(ws + off);                  // B*A int
    off += (size_t)BB * AA * sizeof(int);
    float*              assigned_align = (float*)(ws + off);                // B*A float
    off += (size_t)BB * AA * sizeof(float);
    unsigned int*       maxmet         = (unsigned int*)(ws + off);         // B*M
    off += (size_t)BB * MM * sizeof(unsigned int);
    unsigned int*       maxiou         = (unsigned int*)(ws + off);         // B*M
    off += (size_t)BB * MM * sizeof(unsigned int);

    hipMemsetAsync(mask64, 0, (size_t)BB * AA * sizeof(unsigned long long), stream);
    hipMemsetAsync(maxmet, 0, (size_t)BB * MM * sizeof(unsigned int) * 2, stream);

    float* out = (float*)d_out;
    float* out_labels = out;                         // B*A
    float* out_bboxes = out + (size_t)BB * AA;       // B*A*4
    float* out_scores = out + (size_t)BB * AA * 5;   // B*A*80

    topk_kernel<<<BB * MM, 256, 0, stream>>>(
        pred_scores, pred_bboxes, anchors, gt_labels, gt_bboxes, pad_mask, topk_idx);

    int n2 = BB * MM * KTOP;
    scatter_kernel<<<(n2 + 255) / 256, 256, 0, stream>>>(
        topk_idx, anchors, gt_bboxes, pad_mask, mask64);

    int n3 = BB * AA;
    resolve_kernel<<<(n3 + 255) / 256, 256, 0, stream>>>(
        pred_scores, pred_bboxes, gt_labels, gt_bboxes, bg_ptr, mask64,
        out_labels, out_bboxes, assigned_m, assigned_align, maxmet, maxiou);

    int n4 = BB * AA * (CC / 4);
    scores_kernel<<<(n4 + 255) / 256, 256, 0, stream>>>(
        gt_labels, assigned_m, assigned_align, maxmet, maxiou, out_scores);
}

// Round 2
// 326.879 us; speedup vs baseline: 1.1581x; 1.1581x over previous
//
#include <hip/hip_runtime.h>
#include <stdint.h>

#define BB 32
#define AA 8400
#define CC 80
#define MM 64
#define KTOP 13
#define FEPS 1e-9f

#define NCHB 16                    // k1 blocks per batch
#define WPB 4                      // waves (chunks) per block
#define NCH (NCHB * WPB)           // 64 anchor chunks
#define CH ((AA + NCH - 1) / NCH)  // 132 anchors per chunk
#define NCAND (NCHB * KTOP)        // 208 merge candidates per (b,m)

__device__ __forceinline__ float iou_fn(float gx1, float gy1, float gx2, float gy2,
                                        float px1, float py1, float px2, float py2) {
    float ix1 = fmaxf(gx1, px1), iy1 = fmaxf(gy1, py1);
    float ix2 = fminf(gx2, px2), iy2 = fminf(gy2, py2);
    float ov = fmaxf(ix2 - ix1, 0.0f) * fmaxf(iy2 - iy1, 0.0f);
    float a1 = fmaxf(gx2 - gx1, 0.0f) * fmaxf(gy2 - gy1, 0.0f);
    float a2 = fmaxf(px2 - px1, 0.0f) * fmaxf(py2 - py1, 0.0f);
    return ov / (a1 + a2 - ov + FEPS);
}

// Kernel 1: lane = m. Each wave owns one anchor chunk; per anchor it reads the
// 320B score row once (dense use across lanes) + uniform bbox/anchor loads.
// Per-lane register top-13 with strict-> insertion (JAX tie semantics: lower
// index wins on equal value). In-block 4-way merge -> 13 candidates per chunk.
__global__ __launch_bounds__(256) void topk_part_kernel(
    const float* __restrict__ pred_scores, const float* __restrict__ pred_bboxes,
    const float* __restrict__ anchors, const int* __restrict__ gt_labels,
    const float* __restrict__ gt_bboxes,
    float* __restrict__ part_v, int* __restrict__ part_i)
{
    __shared__ float sv[WPB][MM][KTOP];
    __shared__ int   si[WPB][MM][KTOP];
    int bx = blockIdx.x;
    int b = bx / NCHB, cb = bx % NCHB;
    int t = threadIdx.x, wave = t >> 6, m = t & 63;
    int bm = b * MM + m;
    float gx1 = gt_bboxes[bm * 4 + 0], gy1 = gt_bboxes[bm * 4 + 1];
    float gx2 = gt_bboxes[bm * 4 + 2], gy2 = gt_bboxes[bm * 4 + 3];
    int lab = gt_labels[bm];
    const float* pb = pred_bboxes + (size_t)b * AA * 4;
    const float* ps = pred_scores + (size_t)b * AA * CC + lab;

    float tv[KTOP]; int ti[KTOP];
    #pragma unroll
    for (int k = 0; k < KTOP; ++k) { tv[k] = -1.0f; ti[k] = AA; }

    int ch = cb * WPB + wave;
    int a0 = ch * CH, a1 = min(a0 + CH, AA);
    for (int a = a0; a < a1; ++a) {
        float4 p = *(const float4*)(pb + (size_t)a * 4);
        float px = anchors[a * 2 + 0], py = anchors[a * 2 + 1];
        float iou = iou_fn(gx1, gy1, gx2, gy2, p.x, p.y, p.z, p.w);
        float d = fminf(fminf(px - gx1, py - gy1), fminf(gx2 - px, gy2 - py));
        float s = ps[(size_t)a * CC];
        float i2 = iou * iou;
        float al = s * (i2 * i2 * i2);
        float v = (d > FEPS) ? al : 0.0f;
        if (v > tv[KTOP - 1]) {          // strict >: keeps earliest (lowest a) on ties
            tv[KTOP - 1] = v; ti[KTOP - 1] = a;
            #pragma unroll
            for (int j = KTOP - 1; j >= 1; --j) {
                if (tv[j] > tv[j - 1]) { // strict: equal values keep ascending-idx order
                    float fv = tv[j]; tv[j] = tv[j - 1]; tv[j - 1] = fv;
                    int   fi = ti[j]; ti[j] = ti[j - 1]; ti[j - 1] = fi;
                }
            }
        }
    }
    #pragma unroll
    for (int k = 0; k < KTOP; ++k) { sv[wave][m][k] = tv[k]; si[wave][m][k] = ti[k]; }
    __syncthreads();
    if (t < MM) {   // wave 0: per-m 4-way merge of sorted lists -> 13
        int head[WPB] = {0, 0, 0, 0};
        float* outv = part_v + ((size_t)bm * NCHB + cb) * KTOP;
        int*   outi = part_i + ((size_t)bm * NCHB + cb) * KTOP;
        for (int k = 0; k < KTOP; ++k) {
            float bvv = -2.0f; int bii = 1 << 30, bw = 0;
            #pragma unroll
            for (int w = 0; w < WPB; ++w) {
                float vv = sv[w][t][head[w]];
                int   ii = si[w][t][head[w]];
                if (vv > bvv || (vv == bvv && ii < bii)) { bvv = vv; bii = ii; bw = w; }
            }
            head[bw]++;
            outv[k] = bvv; outi[k] = bii;
        }
    }
}

// Kernel 2: per (b,m) wave merges 16x13 candidates -> final top-13, re-checks
// in_gts, scatters bits into per-anchor 64-bit GT-membership mask.
__global__ __launch_bounds__(64) void topk_merge_scatter_kernel(
    const float* __restrict__ part_v, const int* __restrict__ part_i,
    const float* __restrict__ anchors, const float* __restrict__ gt_bboxes,
    const float* __restrict__ pad_mask,
    unsigned long long* __restrict__ mask64)
{
    int bm = blockIdx.x;
    if (pad_mask[bm] == 0.0f) return;
    int b = bm / MM, m = bm % MM;
    __shared__ float cv[NCAND];
    __shared__ int   ci[NCAND];
    int t = threadIdx.x;
    for (int i = t; i < NCAND; i += 64) {
        cv[i] = part_v[(size_t)bm * NCAND + i];
        ci[i] = part_i[(size_t)bm * NCAND + i];
    }
    __syncthreads();
    float gx1 = gt_bboxes[bm * 4 + 0], gy1 = gt_bboxes[bm * 4 + 1];
    float gx2 = gt_bboxes[bm * 4 + 2], gy2 = gt_bboxes[bm * 4 + 3];
    unsigned long long bit = 1ull << m;
    for (int k = 0; k < KTOP; ++k) {
        float bv = -2.0f; int bi = 1 << 30, bs = -1;
        for (int i = t; i < NCAND; i += 64) {
            float v = cv[i];
            if (v > bv || (v == bv && ci[i] < bi)) { bv = v; bi = ci[i]; bs = i; }
        }
        #pragma unroll
        for (int off = 32; off > 0; off >>= 1) {
            float ov = __shfl_xor(bv, off);
            int   oi = __shfl_xor(bi, off);
            int   os = __shfl_xor(bs, off);
            if (ov > bv || (ov == bv && oi < bi)) { bv = ov; bi = oi; bs = os; }
        }
        if (t == 0) {
            cv[bs] = -2.0f;   // eliminate winner
            float px = anchors[bi * 2 + 0], py = anchors[bi * 2 + 1];
            float d = fminf(fminf(px - gx1, py - gy1), fminf(gx2 - px, gy2 - py));
            if (d > FEPS) atomicOr(&mask64[(size_t)b * AA + bi], bit);
        }
        __syncthreads();
    }
}

// Kernel 3: per anchor — resolve multi-assignment via first-argmax of IoU over
// ALL m (incl. padded, as the reference does), write labels/bboxes, record
// assigned m + align, and atomicMax per-GT max_metrics / max_ious.
__global__ void resolve_kernel(
    const float* __restrict__ pred_scores, const float* __restrict__ pred_bboxes,
    const int* __restrict__ gt_labels, const float* __restrict__ gt_bboxes,
    const int* __restrict__ bg_ptr,
    const unsigned long long* __restrict__ mask64,
    float* __restrict__ out_labels, float* __restrict__ out_bboxes,
    int* __restrict__ assigned_m, float* __restrict__ assigned_align,
    unsigned int* __restrict__ maxmet, unsigned int* __restrict__ maxiou)
{
    int t = blockIdx.x * blockDim.x + threadIdx.x;
    if (t >= BB * AA) return;
    int b = t / AA;
    unsigned long long mask = mask64[t];
    int cnt = __popcll(mask);
    float4 p = *(const float4*)(pred_bboxes + (size_t)t * 4);
    int mstar = -1;
    if (cnt == 1) {
        mstar = __ffsll(mask) - 1;
    } else if (cnt > 1) {
        float best = -1.0f; int bi = 0;
        for (int m = 0; m < MM; ++m) {
            const float* g = gt_bboxes + (size_t)(b * MM + m) * 4;
            float iou = iou_fn(g[0], g[1], g[2], g[3], p.x, p.y, p.z, p.w);
            if (iou > best) { best = iou; bi = m; }   // strict > : first occurrence
        }
        mstar = bi;
    }
    assigned_m[t] = mstar;
    int bidx = (mstar >= 0) ? mstar : 0;   // argmax of all-zero column = 0
    const float* g = gt_bboxes + (size_t)(b * MM + bidx) * 4;
    float g0 = g[0], g1 = g[1], g2 = g[2], g3 = g[3];
    out_bboxes[(size_t)t * 4 + 0] = g0;
    out_bboxes[(size_t)t * 4 + 1] = g1;
    out_bboxes[(size_t)t * 4 + 2] = g2;
    out_bboxes[(size_t)t * 4 + 3] = g3;
    out_labels[t] = (mstar >= 0) ? (float)gt_labels[b * MM + mstar] : (float)(*bg_ptr);
    if (mstar >= 0) {
        float iou = iou_fn(g0, g1, g2, g3, p.x, p.y, p.z, p.w);
        int label = gt_labels[b * MM + mstar];
        int a = t % AA;
        float s = pred_scores[(size_t)b * AA * CC + (size_t)a * CC + label];
        float i2 = iou * iou;
        float al = s * (i2 * i2 * i2);
        assigned_align[t] = al;
        atomicMax(&maxmet[b * MM + mstar], __float_as_uint(al));
        atomicMax(&maxiou[b * MM + mstar], __float_as_uint(iou));
    }
}

// Kernel 4: write assigned_scores (B,A,80) as coalesced float4s.
__global__ void scores_kernel(
    const int* __restrict__ gt_labels,
    const int* __restrict__ assigned_m, const float* __restrict__ assigned_align,
    const unsigned int* __restrict__ maxmet, const unsigned int* __restrict__ maxiou,
    float* __restrict__ out_scores)
{
    int t = blockIdx.x * blockDim.x + threadIdx.x;
    if (t >= BB * AA * (CC / 4)) return;
    int anchor = t / (CC / 4); int j = t % (CC / 4);
    int m = assigned_m[anchor];
    float4 v = make_float4(0.0f, 0.0f, 0.0f, 0.0f);
    if (m >= 0) {
        int b = anchor / AA;
        int label = gt_labels[b * MM + m];
        int base = j * 4;
        if (label >= base && label < base + 4) {
            float mm = __uint_as_float(maxmet[b * MM + m]);
            float mi = __uint_as_float(maxiou[b * MM + m]);
            float scale = assigned_align[anchor] / (mm + FEPS) * mi;
            ((float*)&v)[label - base] = scale;
        }
    }
    *(float4*)(out_scores + (size_t)t * 4) = v;
}

extern "C" void kernel_launch(void* const* d_in, const int* in_sizes, int n_in,
                              void* d_out, int out_size, void* d_ws, size_t ws_size,
                              hipStream_t stream) {
    const float* pred_scores = (const float*)d_in[0];
    const float* pred_bboxes = (const float*)d_in[1];
    const float* anchors     = (const float*)d_in[2];
    const int*   gt_labels   = (const int*)d_in[3];
    const float* gt_bboxes   = (const float*)d_in[4];
    const float* pad_mask    = (const float*)d_in[5];
    const int*   bg_ptr      = (const int*)d_in[6];

    // Workspace layout
    char* ws = (char*)d_ws;
    size_t off = 0;
    float* part_v = (float*)(ws + off);                 // B*M*208 floats
    off += (size_t)BB * MM * NCAND * sizeof(float);
    int*   part_i = (int*)(ws + off);                   // B*M*208 ints
    off += (size_t)BB * MM * NCAND * sizeof(int);
    off = (off + 7) & ~(size_t)7;
    unsigned long long* mask64 = (unsigned long long*)(ws + off);   // B*A u64
    off += (size_t)BB * AA * sizeof(unsigned long long);
    int*   assigned_m     = (int*)(ws + off);           // B*A int
    off += (size_t)BB * AA * sizeof(int);
    float* assigned_align = (float*)(ws + off);         // B*A float
    off += (size_t)BB * AA * sizeof(float);
    unsigned int* maxmet  = (unsigned int*)(ws + off);  // B*M
    off += (size_t)BB * MM * sizeof(unsigned int);
    unsigned int* maxiou  = (unsigned int*)(ws + off);  // B*M
    off += (size_t)BB * MM * sizeof(unsigned int);

    hipMemsetAsync(mask64, 0, (size_t)BB * AA * sizeof(unsigned long long), stream);
    hipMemsetAsync(maxmet, 0, (size_t)BB * MM * sizeof(unsigned int) * 2, stream);

    float* out = (float*)d_out;
    float* out_labels = out;                         // B*A
    float* out_bboxes = out + (size_t)BB * AA;       // B*A*4
    float* out_scores = out + (size_t)BB * AA * 5;   // B*A*80

    topk_part_kernel<<<BB * NCHB, 256, 0, stream>>>(
        pred_scores, pred_bboxes, anchors, gt_labels, gt_bboxes, part_v, part_i);

    topk_merge_scatter_kernel<<<BB * MM, 64, 0, stream>>>(
        part_v, part_i, anchors, gt_bboxes, pad_mask, mask64);

    int n3 = BB * AA;
    resolve_kernel<<<(n3 + 255) / 256, 256, 0, stream>>>(
        pred_scores, pred_bboxes, gt_labels, gt_bboxes, bg_ptr, mask64,
        out_labels, out_bboxes, assigned_m, assigned_align, maxmet, maxiou);

    int n4 = BB * AA * (CC / 4);
    scores_kernel<<<(n4 + 255) / 256, 256, 0, stream>>>(
        gt_labels, assigned_m, assigned_align, maxmet, maxiou, out_scores);
}

// Round 3
// 265.443 us; speedup vs baseline: 1.4262x; 1.2314x over previous
//
#include <hip/hip_runtime.h>
#include <stdint.h>

#define BB 32
#define AA 8400
#define CC 80
#define MM 64
#define KTOP 13
#define FEPS 1e-9f

#define NCHB 32                    // k1 blocks per batch
#define WPB 8                      // waves (chunks) per block -> 512 threads
#define NCH (NCHB * WPB)           // 256 anchor chunks per batch
#define CH ((AA + NCH - 1) / NCH)  // 33 anchors per chunk
#define NCAND (NCHB * KTOP)        // 416 merge candidates per (b,m), 32 sorted lists

__device__ __forceinline__ float iou_fn(float gx1, float gy1, float gx2, float gy2,
                                        float px1, float py1, float px2, float py2) {
    float ix1 = fmaxf(gx1, px1), iy1 = fmaxf(gy1, py1);
    float ix2 = fminf(gx2, px2), iy2 = fminf(gy2, py2);
    float ov = fmaxf(ix2 - ix1, 0.0f) * fmaxf(iy2 - iy1, 0.0f);
    float a1 = fmaxf(gx2 - gx1, 0.0f) * fmaxf(gy2 - gy1, 0.0f);
    float a2 = fmaxf(px2 - px1, 0.0f) * fmaxf(py2 - py1, 0.0f);
    return ov / (a1 + a2 - ov + FEPS);
}

// Kernel 1: lane = m, wave = anchor chunk (33 anchors). Per-lane register
// top-13 (strict-> insertion keeps JAX tie semantics: lower index wins).
// In-block 8-way merge -> one sorted 13-list per (block, m).
// Also zero-fills mask64 / maxmet / maxiou (removes 2 memset dispatches).
__global__ __launch_bounds__(512) void topk_part_kernel(
    const float* __restrict__ pred_scores, const float* __restrict__ pred_bboxes,
    const float* __restrict__ anchors, const int* __restrict__ gt_labels,
    const float* __restrict__ gt_bboxes,
    float* __restrict__ part_v, unsigned short* __restrict__ part_i,
    unsigned long long* __restrict__ mask64,
    unsigned int* __restrict__ maxmet, unsigned int* __restrict__ maxiou)
{
    __shared__ float          sv[WPB][MM][KTOP];
    __shared__ unsigned short si[WPB][MM][KTOP];
    int bx = blockIdx.x;
    int t = threadIdx.x;

    // fused zero-init (consumed by later kernels in-stream)
    {
        int gid = bx * 512 + t;
        if (gid < BB * AA) mask64[gid] = 0ull;
        if (gid < BB * MM) { maxmet[gid] = 0u; maxiou[gid] = 0u; }
    }

    int b = bx / NCHB, cb = bx % NCHB;
    int wave = t >> 6, m = t & 63;
    int bm = b * MM + m;
    float gx1 = gt_bboxes[bm * 4 + 0], gy1 = gt_bboxes[bm * 4 + 1];
    float gx2 = gt_bboxes[bm * 4 + 2], gy2 = gt_bboxes[bm * 4 + 3];
    float garea = (gx2 - gx1) * (gy2 - gy1);   // gt w,h > 0 by construction
    int lab = gt_labels[bm];
    const float* pb = pred_bboxes + (size_t)b * AA * 4;
    const float* ps = pred_scores + (size_t)b * AA * CC + lab;

    float tv[KTOP]; int ti[KTOP];
    #pragma unroll
    for (int k = 0; k < KTOP; ++k) { tv[k] = -1.0f; ti[k] = AA; }

    int ch = cb * WPB + wave;
    int a0 = ch * CH, a1 = min(a0 + CH, AA);
    for (int a = a0; a < a1; ++a) {
        float4 p = *(const float4*)(pb + (size_t)a * 4);   // wave-uniform
        float px = anchors[a * 2 + 0], py = anchors[a * 2 + 1];
        float s = ps[(size_t)a * CC];                      // per-lane, dense in row
        float ix1 = fmaxf(gx1, p.x), iy1 = fmaxf(gy1, p.y);
        float ix2 = fminf(gx2, p.z), iy2 = fminf(gy2, p.w);
        float ov = fmaxf(ix2 - ix1, 0.0f) * fmaxf(iy2 - iy1, 0.0f);
        float parea = (p.z - p.x) * (p.w - p.y);           // pred w,h > 0
        float iou = ov / (garea + parea - ov + FEPS);
        float d = fminf(fminf(px - gx1, py - gy1), fminf(gx2 - px, gy2 - py));
        float i2 = iou * iou;
        float al = s * (i2 * i2 * i2);
        float v = (d > FEPS) ? al : 0.0f;
        if (v > tv[KTOP - 1]) {          // strict >: earliest index wins ties
            tv[KTOP - 1] = v; ti[KTOP - 1] = a;
            #pragma unroll
            for (int j = KTOP - 1; j >= 1; --j) {
                if (tv[j] > tv[j - 1]) {
                    float fv = tv[j]; tv[j] = tv[j - 1]; tv[j - 1] = fv;
                    int   fi = ti[j]; ti[j] = ti[j - 1]; ti[j - 1] = fi;
                }
            }
        }
    }
    #pragma unroll
    for (int k = 0; k < KTOP; ++k) {
        sv[wave][m][k] = tv[k];
        si[wave][m][k] = (unsigned short)ti[k];
    }
    __syncthreads();
    if (t < MM) {   // wave 0: per-m 8-way merge of sorted lists -> sorted 13
        int head[WPB];
        #pragma unroll
        for (int w = 0; w < WPB; ++w) head[w] = 0;
        float* outv = part_v + ((size_t)bm * NCHB + cb) * KTOP;
        unsigned short* outi = part_i + ((size_t)bm * NCHB + cb) * KTOP;
        for (int k = 0; k < KTOP; ++k) {
            float bvv = -2.0f; int bii = 1 << 30, bw = 0;
            #pragma unroll
            for (int w = 0; w < WPB; ++w) {
                float vv = sv[w][t][head[w]];
                int   ii = si[w][t][head[w]];
                if (vv > bvv || (vv == bvv && ii < bii)) { bvv = vv; bii = ii; bw = w; }
            }
            #pragma unroll
            for (int w = 0; w < WPB; ++w) head[w] += (w == bw);
            outv[k] = bvv; outi[k] = (unsigned short)bii;
        }
    }
}

// Kernel 2: per (b,m) wave. 32 sorted 13-lists; lane l<32 owns list l and
// proposes its head each round; shuffle-argmax picks global winner (JAX tie
// semantics), winner's head advances. Lane k captures round-k winner, then
// lanes 0..12 re-check in_gts and scatter bits into the per-anchor GT mask.
__global__ __launch_bounds__(64) void topk_merge_scatter_kernel(
    const float* __restrict__ part_v, const unsigned short* __restrict__ part_i,
    const float* __restrict__ anchors, const float* __restrict__ gt_bboxes,
    const float* __restrict__ pad_mask,
    unsigned long long* __restrict__ mask64)
{
    int bm = blockIdx.x;
    if (pad_mask[bm] == 0.0f) return;
    int b = bm / MM, m = bm % MM;
    __shared__ float          cv[NCAND];
    __shared__ unsigned short ci[NCAND];
    int t = threadIdx.x;
    for (int i = t; i < NCAND; i += 64) {
        cv[i] = part_v[(size_t)bm * NCAND + i];
        ci[i] = part_i[(size_t)bm * NCAND + i];
    }
    __syncthreads();
    int head = 0;
    int mywin = -1;
    for (int k = 0; k < KTOP; ++k) {
        float bv; int bi;
        if (t < NCHB) {          // head <= k <= 12, in-bounds
            bv = cv[t * KTOP + head];
            bi = ci[t * KTOP + head];
        } else { bv = -3.0f; bi = 1 << 30; }
        int bl = t;
        #pragma unroll
        for (int off = 32; off > 0; off >>= 1) {
            float ov = __shfl_xor(bv, off);
            int   oi = __shfl_xor(bi, off);
            int   ol = __shfl_xor(bl, off);
            if (ov > bv || (ov == bv && oi < bi)) { bv = ov; bi = oi; bl = ol; }
        }
        if (t == bl) head++;     // all lanes agree on winner
        if (t == k) mywin = bi;
    }
    if (t < KTOP) {
        int a = mywin;
        float gx1 = gt_bboxes[bm * 4 + 0], gy1 = gt_bboxes[bm * 4 + 1];
        float gx2 = gt_bboxes[bm * 4 + 2], gy2 = gt_bboxes[bm * 4 + 3];
        float px = anchors[a * 2 + 0], py = anchors[a * 2 + 1];
        float d = fminf(fminf(px - gx1, py - gy1), fminf(gx2 - px, gy2 - py));
        if (d > FEPS) atomicOr(&mask64[(size_t)b * AA + a], 1ull << m);
    }
}

// Kernel 3: per anchor — resolve multi-assignment via first-argmax of IoU over
// ALL m (incl. padded, as the reference does), write labels/bboxes, record
// assigned m + align, and atomicMax per-GT max_metrics / max_ious.
__global__ void resolve_kernel(
    const float* __restrict__ pred_scores, const float* __restrict__ pred_bboxes,
    const int* __restrict__ gt_labels, const float* __restrict__ gt_bboxes,
    const int* __restrict__ bg_ptr,
    const unsigned long long* __restrict__ mask64,
    float* __restrict__ out_labels, float* __restrict__ out_bboxes,
    int* __restrict__ assigned_m, float* __restrict__ assigned_align,
    unsigned int* __restrict__ maxmet, unsigned int* __restrict__ maxiou)
{
    int t = blockIdx.x * blockDim.x + threadIdx.x;
    if (t >= BB * AA) return;
    int b = t / AA;
    unsigned long long mask = mask64[t];
    int cnt = __popcll(mask);
    float4 p = *(const float4*)(pred_bboxes + (size_t)t * 4);
    int mstar = -1;
    if (cnt == 1) {
        mstar = __ffsll(mask) - 1;
    } else if (cnt > 1) {
        float best = -1.0f; int bi = 0;
        for (int m = 0; m < MM; ++m) {
            const float* g = gt_bboxes + (size_t)(b * MM + m) * 4;
            float iou = iou_fn(g[0], g[1], g[2], g[3], p.x, p.y, p.z, p.w);
            if (iou > best) { best = iou; bi = m; }   // strict > : first occurrence
        }
        mstar = bi;
    }
    assigned_m[t] = mstar;
    int bidx = (mstar >= 0) ? mstar : 0;   // argmax of all-zero column = 0
    const float* g = gt_bboxes + (size_t)(b * MM + bidx) * 4;
    float g0 = g[0], g1 = g[1], g2 = g[2], g3 = g[3];
    out_bboxes[(size_t)t * 4 + 0] = g0;
    out_bboxes[(size_t)t * 4 + 1] = g1;
    out_bboxes[(size_t)t * 4 + 2] = g2;
    out_bboxes[(size_t)t * 4 + 3] = g3;
    out_labels[t] = (mstar >= 0) ? (float)gt_labels[b * MM + mstar] : (float)(*bg_ptr);
    if (mstar >= 0) {
        float iou = iou_fn(g0, g1, g2, g3, p.x, p.y, p.z, p.w);
        int label = gt_labels[b * MM + mstar];
        int a = t % AA;
        float s = pred_scores[(size_t)b * AA * CC + (size_t)a * CC + label];
        float i2 = iou * iou;
        float al = s * (i2 * i2 * i2);
        assigned_align[t] = al;
        atomicMax(&maxmet[b * MM + mstar], __float_as_uint(al));
        atomicMax(&maxiou[b * MM + mstar], __float_as_uint(iou));
    }
}

// Kernel 4: write assigned_scores (B,A,80) as coalesced float4s.
__global__ void scores_kernel(
    const int* __restrict__ gt_labels,
    const int* __restrict__ assigned_m, const float* __restrict__ assigned_align,
    const unsigned int* __restrict__ maxmet, const unsigned int* __restrict__ maxiou,
    float* __restrict__ out_scores)
{
    int t = blockIdx.x * blockDim.x + threadIdx.x;
    if (t >= BB * AA * (CC / 4)) return;
    int anchor = t / (CC / 4); int j = t % (CC / 4);
    int m = assigned_m[anchor];
    float4 v = make_float4(0.0f, 0.0f, 0.0f, 0.0f);
    if (m >= 0) {
        int b = anchor / AA;
        int label = gt_labels[b * MM + m];
        int base = j * 4;
        if (label >= base && label < base + 4) {
            float mm = __uint_as_float(maxmet[b * MM + m]);
            float mi = __uint_as_float(maxiou[b * MM + m]);
            float scale = assigned_align[anchor] / (mm + FEPS) * mi;
            ((float*)&v)[label - base] = scale;
        }
    }
    *(float4*)(out_scores + (size_t)t * 4) = v;
}

extern "C" void kernel_launch(void* const* d_in, const int* in_sizes, int n_in,
                              void* d_out, int out_size, void* d_ws, size_t ws_size,
                              hipStream_t stream) {
    const float* pred_scores = (const float*)d_in[0];
    const float* pred_bboxes = (const float*)d_in[1];
    const float* anchors     = (const float*)d_in[2];
    const int*   gt_labels   = (const int*)d_in[3];
    const float* gt_bboxes   = (const float*)d_in[4];
    const float* pad_mask    = (const float*)d_in[5];
    const int*   bg_ptr      = (const int*)d_in[6];

    // Workspace layout (~9.5 MB)
    char* ws = (char*)d_ws;
    size_t off = 0;
    float* part_v = (float*)(ws + off);                 // B*M*416 floats
    off += (size_t)BB * MM * NCAND * sizeof(float);
    unsigned short* part_i = (unsigned short*)(ws + off);   // B*M*416 u16
    off += (size_t)BB * MM * NCAND * sizeof(unsigned short);
    off = (off + 7) & ~(size_t)7;
    unsigned long long* mask64 = (unsigned long long*)(ws + off);   // B*A u64
    off += (size_t)BB * AA * sizeof(unsigned long long);
    int*   assigned_m     = (int*)(ws + off);           // B*A int
    off += (size_t)BB * AA * sizeof(int);
    float* assigned_align = (float*)(ws + off);         // B*A float
    off += (size_t)BB * AA * sizeof(float);
    unsigned int* maxmet  = (unsigned int*)(ws + off);  // B*M
    off += (size_t)BB * MM * sizeof(unsigned int);
    unsigned int* maxiou  = (unsigned int*)(ws + off);  // B*M
    off += (size_t)BB * MM * sizeof(unsigned int);

    float* out = (float*)d_out;
    float* out_labels = out;                         // B*A
    float* out_bboxes = out + (size_t)BB * AA;       // B*A*4
    float* out_scores = out + (size_t)BB * AA * 5;   // B*A*80

    topk_part_kernel<<<BB * NCHB, 512, 0, stream>>>(
        pred_scores, pred_bboxes, anchors, gt_labels, gt_bboxes,
        part_v, part_i, mask64, maxmet, maxiou);

    topk_merge_scatter_kernel<<<BB * MM, 64, 0, stream>>>(
        part_v, part_i, anchors, gt_bboxes, pad_mask, mask64);

    int n3 = BB * AA;
    resolve_kernel<<<(n3 + 255) / 256, 256, 0, stream>>>(
        pred_scores, pred_bboxes, gt_labels, gt_bboxes, bg_ptr, mask64,
        out_labels, out_bboxes, assigned_m, assigned_align, maxmet, maxiou);

    int n4 = BB * AA * (CC / 4);
    scores_kernel<<<(n4 + 255) / 256, 256, 0, stream>>>(
        gt_labels, assigned_m, assigned_align, maxmet, maxiou, out_scores);
}